// Round 1
// baseline (557.629 us; speedup 1.0000x reference)
//
#include <hip/hip_runtime.h>
#include <hip/hip_bf16.h>
#include <hip/hip_cooperative_groups.h>

namespace cg = cooperative_groups;

#define DIM   128
#define NREL  3
#define KS    (NREL*DIM)     // 384
#define NB    16             // nodes per block in main kernel
#define LN_EPS 1e-5f
#define SCHUNK 1024          // scan elements per scan-chunk
#define PBLK  1024           // cooperative grid blocks (4/CU @ 256thr — safely co-resident)
#define PTHR  256
#define REG_E 8              // edges held in registers per thread: E <= REG_E*PBLK*PTHR = 2.09M

typedef unsigned int uint;
typedef float f32x4 __attribute__((ext_vector_type(4)));
typedef short short8 __attribute__((ext_vector_type(8)));

__device__ __forceinline__ unsigned short f2bf(float f) {   // round-to-nearest-even
    union { float f; uint u; } c; c.f = f;
    return (unsigned short)((c.u + 0x7fffu + ((c.u >> 16) & 1u)) >> 16);
}
__device__ __forceinline__ uint packbf(float a, float b) {
    return (uint)f2bf(a) | ((uint)f2bf(b) << 16);
}
// Index element i from an "int" input that may really be int64 (i64 flag)
__device__ __forceinline__ int ldidx(const int* p, size_t i, int i64) {
    return i64 ? p[2*i] : p[i];
}
// 16B-slot offset of A-frag holding A[m][k..k+7] (k%8==0), 16-row tile,
// mfma_f32_16x16x32_bf16: slot = (k>>5)*64 + ((k>>3)&3)*16 + m
__device__ __forceinline__ int fo(int m, int k) {
    return ((k >> 5) << 6) + ((((k >> 3) & 3)) << 4) + m;
}
// Bank swizzle: XOR bits>=4 into bits 0-2. Bijective; kills the 8-way
// same-m write conflict while leaving MFMA reads at the free 2-lanes/bank.
__device__ __forceinline__ int SW(int s) { return s ^ ((s >> 4) & 7); }

// ---------------------------------------------------------------------------
// Cooperative prologue: ONE launch replaces memset+probe+prep+scan_p1+
// scan_p23+fillf.  Key idea: the histogram atomicAdd's RETURN VALUE is the
// edge's rank within its (dst,rel) bucket; holding (src,bucket,rank) in
// registers across grid.sync() makes the fill a plain store — 600K atomics
// total instead of 1.2M, and zero intermediate global round-trips.
// Phases:  0: zero work + B-pack + per-block int64 probe
//          1: hist (atomic rank into registers)
//          2: scan A (chunk sums -> part)
//          3: scan B (exclusive starts in place)
//          4: fill epack[start+rank]=src, sentinel work[M3]=E
// After this kernel, work[] holds exclusive bucket STARTS (+ sentinel).
// ---------------------------------------------------------------------------
__global__ __launch_bounds__(PTHR)
void prologue_kernel(const int* __restrict__ ei, const int* __restrict__ et,
                     int E, int M3, int NBLK,
                     int* __restrict__ work, int* __restrict__ part,
                     const float* __restrict__ relw, const float* __restrict__ linw,
                     unsigned short* __restrict__ Bpack, int* __restrict__ epack)
{
    cg::grid_group grid = cg::this_grid();
    const int t    = threadIdx.x;
    const int b    = blockIdx.x;
    const int tid  = b * PTHR + t;
    const int nthr = PBLK * PTHR;

    // ---- phase 0: int64 probe (per-block, redundant, L2-broadcast) ----
    __shared__ int s_i64;
    if (t < 64) {
        int z = 0;
        #pragma unroll
        for (int i = 0; i < 4; i++) z += (ei[t*4 + i] == 0) ? 1 : 0;
        #pragma unroll
        for (int off = 1; off < 64; off <<= 1) z += __shfl_xor(z, off);
        if (t == 0) s_i64 = (z > 64) ? 1 : 0;
    }

    // zero the bucket counters
    for (int i = tid; i < M3; i += nthr) work[i] = 0;

    // fused B-pack: Wbig (fp32) -> bf16 B-fragment order, 8192 uint4
    // Wbig[k][n]: k<384 -> relation_weights[k*128+n]; k>=384 -> lin_w[n*128+(k-384)]
    if (tid < 8192) {
        int idx = tid;
        int lane = idx & 63, kk = (idx >> 6) & 15, tile = idx >> 10;
        int q = lane >> 4, n = tile * 16 + (lane & 15);
        uint vv[4];
        #pragma unroll
        for (int jp = 0; jp < 4; jp++) {
            int k0 = kk * 32 + q * 8 + jp * 2;
            float v0 = (k0     < KS) ? relw[(size_t)k0*DIM + n]
                                     : linw[(size_t)n*DIM + (k0 - KS)];
            float v1 = (k0 + 1 < KS) ? relw[(size_t)(k0+1)*DIM + n]
                                     : linw[(size_t)n*DIM + (k0 + 1 - KS)];
            vv[jp] = packbf(v0, v1);
        }
        uint4 v; v.x = vv[0]; v.y = vv[1]; v.z = vv[2]; v.w = vv[3];
        ((uint4*)Bpack)[idx] = v;
    }

    grid.sync();
    const int i64 = s_i64;

    // ---- phase 1: histogram; keep (src,bucket,rank) in registers ----
    int sreg[REG_E], breg[REG_E], rk[REG_E];
    #pragma unroll
    for (int i = 0; i < REG_E; i++) {
        breg[i] = -1; sreg[i] = 0; rk[i] = 0;
        int e = tid + i * nthr;
        if (e < E) {
            int s = ldidx(ei, (size_t)e, i64);
            int d = ldidx(ei, (size_t)E + e, i64);
            int r = ldidx(et, (size_t)e, i64);
            int bb = d * 3 + r;
            sreg[i] = s; breg[i] = bb;
            rk[i] = atomicAdd(&work[bb], 1);     // old value == rank in bucket
        }
    }

    grid.sync();

    // ---- phase 2: per-chunk sums ----
    __shared__ int red[256];
    if (b < NBLK) {
        int base = b * SCHUNK + t * 4;
        int s = 0;
        if (base + 3 < M3) {
            int4 v = *(const int4*)(work + base);
            s = v.x + v.y + v.z + v.w;
        } else {
            for (int i = 0; i < 4; i++) if (base + i < M3) s += work[base + i];
        }
        red[t] = s;
        __syncthreads();
        for (int off = 128; off > 0; off >>= 1) {
            if (t < off) red[t] += red[t + off];
            __syncthreads();
        }
        if (t == 0) part[b] = red[0];
    }

    grid.sync();

    // ---- phase 3: exclusive starts, in place (NBLK <= 256 required) ----
    __shared__ int shp[256];
    __shared__ int sh[256];
    if (b < NBLK) {
        shp[t] = (t < NBLK) ? part[t] : 0;
        __syncthreads();
        for (int off = 1; off < 256; off <<= 1) {
            int v = shp[t];
            int a = (t >= off) ? shp[t - off] : 0;
            __syncthreads();
            shp[t] = v + a;
            __syncthreads();
        }
        int base_b = (b == 0) ? 0 : shp[b - 1];
        int base = b * SCHUNK + t * 4;
        int v[4]; int s = 0;
        #pragma unroll
        for (int i = 0; i < 4; i++) {
            v[i] = (base + i < M3) ? work[base + i] : 0;
            s += v[i];
        }
        sh[t] = s;
        __syncthreads();
        for (int off = 1; off < 256; off <<= 1) {
            int x2 = sh[t];
            int a = (t >= off) ? sh[t - off] : 0;
            __syncthreads();
            sh[t] = x2 + a;
            __syncthreads();
        }
        int run = base_b + ((t == 0) ? 0 : sh[t - 1]);
        #pragma unroll
        for (int i = 0; i < 4; i++) {
            if (base + i < M3) { work[base + i] = run; run += v[i]; }
        }
    }

    grid.sync();

    // ---- phase 4: fill (NO atomics — rank was captured in phase 1) ----
    if (tid == 0) work[M3] = E;                   // sentinel: end of last bucket
    #pragma unroll
    for (int i = 0; i < REG_E; i++) {
        if (breg[i] >= 0)
            epack[work[breg[i]] + rk[i]] = sreg[i];
    }
}

// ---------------------------------------------------------------------------
// Main: bucketed gather (8 thr/node, single acc[16] per relation-run) ->
// swizzled bf16 A-frags in LDS (16KB) -> MFMA -> +bias -> LN -> fp32 out.
// starts[b] = exclusive start of bucket b; starts[M3] = E sentinel.
// ---------------------------------------------------------------------------
__global__ __launch_bounds__(128)
void main_kernel(const float* __restrict__ x,
                 const int* __restrict__ starts,
                 const int* __restrict__ epack,
                 const unsigned short* __restrict__ Bpack,
                 const float* __restrict__ linb,
                 const float* __restrict__ gamma,
                 const float* __restrict__ beta,
                 float* __restrict__ out,
                 int N)
{
    __shared__ uint4 Af[1024];              // 16 KiB: A-frags, reused as H[16][132]
    __shared__ float s_mu[NB], s_rs[NB];

    const int t  = threadIdx.x;             // 0..127
    const int n0 = blockIdx.x * NB;

    // ---------------- gather ----------------
    {
        const int m = t >> 3;               // node-local 0..15
        const int c = t & 7;                // owns dims [16c, 16c+16)
        const int c4 = c * 4;
        const int n = n0 + m;
        int beg[3] = {0,0,0}, en[3] = {0,0,0};
        float inv = 1.0f;
        float xf[16];
        #pragma unroll
        for (int i = 0; i < 16; i++) xf[i] = 0.f;
        const float4* xb = (const float4*)x;      // 32 float4 per 128-dim row
        if (n < N) {
            int b3 = n * 3;
            int p0 = starts[b3], p1 = starts[b3 + 1];
            int p2 = starts[b3 + 2], p3 = starts[b3 + 3];
            beg[0] = p0; en[0] = p1;
            beg[1] = p1; en[1] = p2;
            beg[2] = p2; en[2] = p3;
            inv = 1.0f / fmaxf((float)(p3 - p0), 1.0f);
            #pragma unroll
            for (int i = 0; i < 4; i++) {
                float4 xv = xb[n*32 + c4 + i];
                xf[4*i+0] = xv.x; xf[4*i+1] = xv.y; xf[4*i+2] = xv.z; xf[4*i+3] = xv.w;
            }
        }
        #pragma unroll
        for (int r = 0; r < NREL; r++) {
            float acc[16];
            #pragma unroll
            for (int i = 0; i < 16; i++) acc[i] = 0.f;
            int p = beg[r], pe = en[r];
            for (; p + 1 < pe; p += 2) {            // 2-way unroll for MLP
                int sA = epack[p], sB = epack[p+1];
                float4 u0 = xb[sA*32 + c4 + 0];
                float4 u1 = xb[sA*32 + c4 + 1];
                float4 u2 = xb[sA*32 + c4 + 2];
                float4 u3 = xb[sA*32 + c4 + 3];
                float4 v0 = xb[sB*32 + c4 + 0];
                float4 v1 = xb[sB*32 + c4 + 1];
                float4 v2 = xb[sB*32 + c4 + 2];
                float4 v3 = xb[sB*32 + c4 + 3];
                acc[0]  += u0.x + v0.x; acc[1]  += u0.y + v0.y;
                acc[2]  += u0.z + v0.z; acc[3]  += u0.w + v0.w;
                acc[4]  += u1.x + v1.x; acc[5]  += u1.y + v1.y;
                acc[6]  += u1.z + v1.z; acc[7]  += u1.w + v1.w;
                acc[8]  += u2.x + v2.x; acc[9]  += u2.y + v2.y;
                acc[10] += u2.z + v2.z; acc[11] += u2.w + v2.w;
                acc[12] += u3.x + v3.x; acc[13] += u3.y + v3.y;
                acc[14] += u3.z + v3.z; acc[15] += u3.w + v3.w;
            }
            if (p < pe) {
                int sA = epack[p];
                float4 u0 = xb[sA*32 + c4 + 0];
                float4 u1 = xb[sA*32 + c4 + 1];
                float4 u2 = xb[sA*32 + c4 + 2];
                float4 u3 = xb[sA*32 + c4 + 3];
                acc[0]  += u0.x; acc[1]  += u0.y; acc[2]  += u0.z; acc[3]  += u0.w;
                acc[4]  += u1.x; acc[5]  += u1.y; acc[6]  += u1.z; acc[7]  += u1.w;
                acc[8]  += u2.x; acc[9]  += u2.y; acc[10] += u2.z; acc[11] += u2.w;
                acc[12] += u3.x; acc[13] += u3.y; acc[14] += u3.z; acc[15] += u3.w;
            }
            uint4 w0, w1;
            w0.x = packbf(acc[0]*inv,  acc[1]*inv);  w0.y = packbf(acc[2]*inv,  acc[3]*inv);
            w0.z = packbf(acc[4]*inv,  acc[5]*inv);  w0.w = packbf(acc[6]*inv,  acc[7]*inv);
            w1.x = packbf(acc[8]*inv,  acc[9]*inv);  w1.y = packbf(acc[10]*inv, acc[11]*inv);
            w1.z = packbf(acc[12]*inv, acc[13]*inv); w1.w = packbf(acc[14]*inv, acc[15]*inv);
            int k = r*DIM + 16*c;
            Af[SW(fo(m, k))]     = w0;
            Af[SW(fo(m, k + 8))] = w1;
        }
        {
            uint4 w0, w1;
            w0.x = packbf(xf[0],  xf[1]);  w0.y = packbf(xf[2],  xf[3]);
            w0.z = packbf(xf[4],  xf[5]);  w0.w = packbf(xf[6],  xf[7]);
            w1.x = packbf(xf[8],  xf[9]);  w1.y = packbf(xf[10], xf[11]);
            w1.z = packbf(xf[12], xf[13]); w1.w = packbf(xf[14], xf[15]);
            int k = KS + 16*c;
            Af[SW(fo(m, k))]     = w0;
            Af[SW(fo(m, k + 8))] = w1;
        }
    }
    __syncthreads();

    // ---------------- MFMA GEMM ----------------
    const int lane = t & 63;
    const int w    = t >> 6;                // 0..1 (wave)
    const int mm   = lane & 15;
    const int q    = lane >> 4;
    f32x4 acc0 = {0,0,0,0}, acc1 = {0,0,0,0}, acc2 = {0,0,0,0}, acc3 = {0,0,0,0};
    {
        const short8* Aq = (const short8*)Af;
        const short8* Bq = (const short8*)Bpack;
        #pragma unroll
        for (int kk = 0; kk < 16; kk++) {
            short8 a  = Aq[SW(kk*64 + lane)];
            short8 b0 = Bq[((w*4 + 0)*16 + kk)*64 + lane];
            short8 b1 = Bq[((w*4 + 1)*16 + kk)*64 + lane];
            short8 b2 = Bq[((w*4 + 2)*16 + kk)*64 + lane];
            short8 b3 = Bq[((w*4 + 3)*16 + kk)*64 + lane];
            acc0 = __builtin_amdgcn_mfma_f32_16x16x32_bf16(a, b0, acc0, 0, 0, 0);
            acc1 = __builtin_amdgcn_mfma_f32_16x16x32_bf16(a, b1, acc1, 0, 0, 0);
            acc2 = __builtin_amdgcn_mfma_f32_16x16x32_bf16(a, b2, acc2, 0, 0, 0);
            acc3 = __builtin_amdgcn_mfma_f32_16x16x32_bf16(a, b3, acc3, 0, 0, 0);
        }
    }
    __syncthreads();                        // all A reads done; reuse as H

    float* H = (float*)Af;                  // H[16][132] = 8448 B < 16 KiB
    {
        int rb = q * 4;
        #pragma unroll
        for (int nt = 0; nt < 4; nt++) {
            int d = (w*4 + nt)*16 + mm;
            float lb = linb[d];
            f32x4 a = (nt == 0) ? acc0 : (nt == 1) ? acc1 : (nt == 2) ? acc2 : acc3;
            #pragma unroll
            for (int i = 0; i < 4; i++)
                H[(rb + i)*132 + d] = a[i] + lb;
        }
    }
    __syncthreads();

    // ---------------- LayerNorm stats ----------------
    {
        int j = t >> 3, p = t & 7;
        float s1 = 0.f, s2 = 0.f;
        const float* hr = &H[j*132 + p*16];
        #pragma unroll
        for (int i = 0; i < 16; i++) { float v = hr[i]; s1 += v; s2 += v*v; }
        #pragma unroll
        for (int off = 1; off < 8; off <<= 1) {
            s1 += __shfl_xor(s1, off);
            s2 += __shfl_xor(s2, off);
        }
        if (p == 0) {
            float mu  = s1 * (1.0f/DIM);
            float var = s2 * (1.0f/DIM) - mu*mu;
            s_mu[j] = mu;
            s_rs[j] = rsqrtf(var + LN_EPS);
        }
    }
    __syncthreads();

    // ---------------- output (fp32) ----------------
    {
        int d = t;
        float g = gamma[d];
        float b = beta[d];
        for (int j = 0; j < NB; j++) {
            int n = n0 + j;
            if (n < N) {
                float hv = H[j*132 + d];
                out[(size_t)n*DIM + d] = g * (hv - s_mu[j]) * s_rs[j] + b;
            }
        }
    }
}

extern "C" void kernel_launch(void* const* d_in, const int* in_sizes, int n_in,
                              void* d_out, int out_size, void* d_ws, size_t ws_size,
                              hipStream_t stream)
{
    const float* x   = (const float*)d_in[0];
    const int*   ei  = (const int*)d_in[1];
    const int*   et  = (const int*)d_in[2];
    const float* rw  = (const float*)d_in[3];
    const float* lw  = (const float*)d_in[4];
    const float* lb  = (const float*)d_in[5];
    const float* lg  = (const float*)d_in[6];
    const float* lbe = (const float*)d_in[7];

    const int N  = in_sizes[0] / DIM;
    const int E  = in_sizes[2];
    const int M3 = 3 * N;
    const int NBLK = (M3 + SCHUNK - 1) / SCHUNK;   // 147 for N=50000 (<=256 required)

    // ws layout — 3.13 MB total (<= known-good 3.26 MB)
    char* w = (char*)d_ws;
    int* part  = (int*)w;                 w += 256 * 4;
    int* work  = (int*)w;                 w += ((size_t)M3 + 4) * 4;   // +sentinel
    int* epack = (int*)w;                 w += (size_t)E * 4;          // 2.4 MB
    w = (char*)(((uintptr_t)w + 15) & ~(uintptr_t)15);
    unsigned short* Bpack = (unsigned short*)w;    w += 512 * 128 * 2; // 128 KB

    int Ev = E, M3v = M3, NBLKv = NBLK;
    void* pargs[] = {
        (void*)&ei, (void*)&et, (void*)&Ev, (void*)&M3v, (void*)&NBLKv,
        (void*)&work, (void*)&part, (void*)&rw, (void*)&lw,
        (void*)&Bpack, (void*)&epack
    };
    hipLaunchCooperativeKernel((const void*)prologue_kernel,
                               dim3(PBLK), dim3(PTHR), pargs, 0, stream);

    main_kernel<<<(N + NB - 1)/NB, 128, 0, stream>>>(x, work, epack, Bpack,
                                                     lb, lg, lbe,
                                                     (float*)d_out, N);
}

// Round 2
// 205.918 us; speedup vs baseline: 2.7080x; 2.7080x over previous
//
#include <hip/hip_runtime.h>
#include <hip/hip_bf16.h>

#define DIM   128
#define NREL  3
#define KS    (NREL*DIM)     // 384
#define NB    16             // nodes per block in main kernel
#define LN_EPS 1e-5f

typedef unsigned int uint;
typedef float f32x4 __attribute__((ext_vector_type(4)));
typedef short short8 __attribute__((ext_vector_type(8)));

__device__ __forceinline__ unsigned short f2bf(float f) {   // round-to-nearest-even
    union { float f; uint u; } c; c.f = f;
    return (unsigned short)((c.u + 0x7fffu + ((c.u >> 16) & 1u)) >> 16);
}
__device__ __forceinline__ uint packbf(float a, float b) {
    return (uint)f2bf(a) | ((uint)f2bf(b) << 16);
}
__device__ __forceinline__ float blo(uint u) {              // low bf16 -> f32
    union { uint u; float f; } c; c.u = u << 16; return c.f;
}
__device__ __forceinline__ float bhi(uint u) {              // high bf16 -> f32
    union { uint u; float f; } c; c.u = u & 0xffff0000u; return c.f;
}
// Index element i from an "int" input that may really be int64 (i64 flag)
__device__ __forceinline__ int ldidx(const int* p, size_t i, int i64) {
    return i64 ? p[2*i] : p[i];
}
// 16B-slot offset of A-frag holding A[m][k..k+7] (k%8==0), 16-row tile,
// mfma_f32_16x16x32_bf16: slot = (k>>5)*64 + ((k>>3)&3)*16 + m
__device__ __forceinline__ int fo(int m, int k) {
    return ((k >> 5) << 6) + ((((k >> 3) & 3)) << 4) + m;
}
// Bank swizzle: XOR bits>=4 into bits 0-2. Bijective; kills the 8-way
// same-m write conflict while leaving MFMA reads at the free 2-lanes/bank.
__device__ __forceinline__ int SW(int s) { return s ^ ((s >> 4) & 7); }

// Per-block int64 probe: int64 storage => ~half of first 256 words are zero.
__device__ __forceinline__ void block_probe(const int* __restrict__ ei, int t, int* s_i64) {
    if (t < 64) {
        int z = 0;
        #pragma unroll
        for (int i = 0; i < 4; i++) z += (ei[t*4 + i] == 0) ? 1 : 0;
        #pragma unroll
        for (int off = 1; off < 64; off <<= 1) z += __shfl_xor(z, off);
        if (t == 0) *s_i64 = (z > 64) ? 1 : 0;
    }
}

// B-pack: Wbig (fp32) -> bf16 B-fragment order, 8192 uint4.
// Wbig[k][n]: k<384 -> relation_weights[k*128+n]; k>=384 -> lin_w[n*128+(k-384)]
__device__ __forceinline__ void bpack_work(int tid, const float* __restrict__ relw,
                                           const float* __restrict__ linw,
                                           unsigned short* __restrict__ Bpack) {
    if (tid < 8192) {
        int idx = tid;
        int lane = idx & 63, kk = (idx >> 6) & 15, tile = idx >> 10;
        int q = lane >> 4, n = tile * 16 + (lane & 15);
        uint vv[4];
        #pragma unroll
        for (int jp = 0; jp < 4; jp++) {
            int k0 = kk * 32 + q * 8 + jp * 2;
            float v0 = (k0     < KS) ? relw[(size_t)k0*DIM + n]
                                     : linw[(size_t)n*DIM + (k0 - KS)];
            float v1 = (k0 + 1 < KS) ? relw[(size_t)(k0+1)*DIM + n]
                                     : linw[(size_t)n*DIM + (k0 + 1 - KS)];
            vv[jp] = packbf(v0, v1);
        }
        uint4 v; v.x = vv[0]; v.y = vv[1]; v.z = vv[2]; v.w = vv[3];
        ((uint4*)Bpack)[idx] = v;
    }
}

// ---------------------------------------------------------------------------
// prep_fast: probe + x->bf16 convert + B-pack + histogram w/ rank capture.
// The atomicAdd return value IS the edge's rank within its (dst,rel) bucket;
// storing it makes the later fill atomic-free.
// ---------------------------------------------------------------------------
__global__ __launch_bounds__(256)
void prep_fast(const int* __restrict__ ei, const int* __restrict__ et,
               const float* __restrict__ x, int E, int N,
               int* __restrict__ work,
               int* __restrict__ dst3, int* __restrict__ srcv, int* __restrict__ rkv,
               const float* __restrict__ relw, const float* __restrict__ linw,
               unsigned short* __restrict__ Bpack, unsigned short* __restrict__ xbf)
{
    __shared__ int s_i64;
    const int t    = threadIdx.x;
    const int tid  = blockIdx.x * 256 + t;
    const int nthr = gridDim.x * 256;

    block_probe(ei, t, &s_i64);

    // x -> bf16, grid-stride; item = 8 floats -> 4 packed uints
    const float4* x4 = (const float4*)x;
    const int items = N * (DIM / 8);
    for (int i = tid; i < items; i += nthr) {
        float4 a = x4[i*2], b = x4[i*2 + 1];
        uint4 v;
        v.x = packbf(a.x, a.y); v.y = packbf(a.z, a.w);
        v.z = packbf(b.x, b.y); v.w = packbf(b.z, b.w);
        ((uint4*)xbf)[i] = v;
    }

    bpack_work(tid, relw, linw, Bpack);
    __syncthreads();
    const int i64 = s_i64;

    int e = tid;
    if (e < E) {
        int s = ldidx(ei, (size_t)e, i64);
        int d = ldidx(ei, (size_t)E + e, i64);
        int r = ldidx(et, (size_t)e, i64);
        int bb = d * 3 + r;
        dst3[e] = bb;
        srcv[e] = s;
        rkv[e]  = atomicAdd(&work[bb], 1);      // old value == rank in bucket
    }
}

// prep_slow: probe + B-pack + histogram only (small-ws fallback).
__global__ __launch_bounds__(256)
void prep_slow(const int* __restrict__ ei, const int* __restrict__ et, int E,
               int* __restrict__ work,
               const float* __restrict__ relw, const float* __restrict__ linw,
               unsigned short* __restrict__ Bpack)
{
    __shared__ int s_i64;
    const int t   = threadIdx.x;
    const int tid = blockIdx.x * 256 + t;
    block_probe(ei, t, &s_i64);
    bpack_work(tid, relw, linw, Bpack);
    __syncthreads();
    const int i64 = s_i64;
    int e = tid;
    if (e < E) {
        int d = ldidx(ei, (size_t)E + e, i64);
        int r = ldidx(et, (size_t)e, i64);
        atomicAdd(&work[d * 3 + r], 1);
    }
}

// ---------------------------------------------------------------------------
// Single-pass decoupled-lookback exclusive scan over work[0..M3).
// part[b] packs {status:2, value:30}; status 1=aggregate, 2=inclusive.
// NO grid barrier: lookback walks predecessors' published words (parallel
// depth, ~µs) instead of a 100µs cooperative sync. part[] zeroed by memset.
// Last block writes work[M3] = total (sentinel used by starts-mode main).
// ---------------------------------------------------------------------------
__global__ __launch_bounds__(256)
void scan_kernel(int* __restrict__ work, uint* __restrict__ part, int M3, int NBLK)
{
    __shared__ int sh[256];
    __shared__ int s_excl;
    const int b = blockIdx.x, t = threadIdx.x;
    const int base = b * 1024 + t * 4;

    int v[4]; int s = 0;
    if (base + 3 < M3) {
        int4 q = *(const int4*)(work + base);
        v[0] = q.x; v[1] = q.y; v[2] = q.z; v[3] = q.w;
        s = q.x + q.y + q.z + q.w;
    } else {
        #pragma unroll
        for (int i = 0; i < 4; i++) {
            v[i] = (base + i < M3) ? work[base + i] : 0;
            s += v[i];
        }
    }
    sh[t] = s;
    __syncthreads();
    for (int off = 1; off < 256; off <<= 1) {       // inclusive Hillis-Steele
        int x2 = sh[t];
        int a = (t >= off) ? sh[t - off] : 0;
        __syncthreads();
        sh[t] = x2 + a;
        __syncthreads();
    }
    const int S = sh[255];

    if (t == 0) {
        int excl = 0;
        if (b == 0) {
            __hip_atomic_store(&part[0], (uint)S | (2u << 30),
                               __ATOMIC_RELEASE, __HIP_MEMORY_SCOPE_AGENT);
        } else {
            __hip_atomic_store(&part[b], (uint)S | (1u << 30),
                               __ATOMIC_RELEASE, __HIP_MEMORY_SCOPE_AGENT);
            int j = b - 1;
            for (;;) {
                uint w = __hip_atomic_load(&part[j],
                                           __ATOMIC_ACQUIRE, __HIP_MEMORY_SCOPE_AGENT);
                uint st = w >> 30;
                if (st == 0u) { __builtin_amdgcn_s_sleep(1); continue; }
                excl += (int)(w & 0x3fffffffu);
                if (st == 2u) break;
                --j;
            }
            __hip_atomic_store(&part[b], (uint)(excl + S) | (2u << 30),
                               __ATOMIC_RELEASE, __HIP_MEMORY_SCOPE_AGENT);
        }
        if (b == NBLK - 1) work[M3] = excl + S;     // sentinel: total == E
        s_excl = excl;
    }
    __syncthreads();

    int run = s_excl + ((t == 0) ? 0 : sh[t - 1]);
    #pragma unroll
    for (int i = 0; i < 4; i++) {
        if (base + i < M3) { work[base + i] = run; run += v[i]; }
    }
}

// fill_fast: NO atomics — rank was captured by prep_fast. work[] stays starts.
__global__ __launch_bounds__(256)
void fill_fast(const int* __restrict__ dst3, const int* __restrict__ srcv,
               const int* __restrict__ rkv, int E,
               const int* __restrict__ starts, int* __restrict__ epack)
{
    int e = blockIdx.x * 256 + threadIdx.x;
    if (e >= E) return;
    epack[starts[dst3[e]] + rkv[e]] = srcv[e];
}

// fill_slow: atomic cursor advance (starts -> ends), re-reads raw ei/et.
__global__ __launch_bounds__(256)
void fill_slow(const int* __restrict__ ei, const int* __restrict__ et, int E,
               int* __restrict__ work, int* __restrict__ epack)
{
    __shared__ int s_i64;
    const int t = threadIdx.x;
    block_probe(ei, t, &s_i64);
    __syncthreads();
    const int i64 = s_i64;
    int e = blockIdx.x * 256 + t;
    if (e >= E) return;
    int s = ldidx(ei, (size_t)e, i64);
    int d = ldidx(ei, (size_t)E + e, i64);
    int r = ldidx(et, (size_t)e, i64);
    int p = atomicAdd(&work[d * 3 + r], 1);
    epack[p] = s;
}

// ---------------------------------------------------------------------------
// Main: bucketed gather (8 thr/node) -> swizzled bf16 A-frags in LDS ->
// MFMA -> +bias -> LN -> fp32 out.
// FAST=1: x is pre-converted bf16 (xbf), bounds[] are exclusive STARTS with
//         sentinel bounds[M3]=E.  Gather reads 256B/row.
// FAST=0: fp32 x, bounds[] are inclusive ENDS (round-0 semantics).
// ---------------------------------------------------------------------------
template<int FAST>
__global__ __launch_bounds__(128)
void main_kernel(const float* __restrict__ x,
                 const unsigned short* __restrict__ xbf,
                 const int* __restrict__ bounds,
                 const int* __restrict__ epack,
                 const unsigned short* __restrict__ Bpack,
                 const float* __restrict__ linb,
                 const float* __restrict__ gamma,
                 const float* __restrict__ beta,
                 float* __restrict__ out,
                 int N)
{
    __shared__ uint4 Af[1024];              // 16 KiB: A-frags, reused as H[16][132]
    __shared__ float s_mu[NB], s_rs[NB];

    const int t  = threadIdx.x;             // 0..127
    const int n0 = blockIdx.x * NB;

    // ---------------- gather ----------------
    {
        const int m = t >> 3;               // node-local 0..15
        const int c = t & 7;                // owns dims [16c, 16c+16)
        const int n = n0 + m;
        int beg[3] = {0,0,0}, en[3] = {0,0,0};
        float inv = 1.0f;
        uint4 r0 = {0,0,0,0}, r1 = {0,0,0,0};        // FAST residual frags
        float xf[16];
        #pragma unroll
        for (int i = 0; i < 16; i++) xf[i] = 0.f;

        const float4* xb = (const float4*)x;         // 32 float4 per row (slow)
        const uint4*  xh = (const uint4*)xbf;        // 16 uint4 per row (fast)
        const int c4 = c * 4;                        // slow: float4 index
        const int c2 = c * 2;                        // fast: uint4 index

        if (n < N) {
            int b3 = n * 3;
            int p0, p1, p2, p3;
            if (FAST) {
                p0 = bounds[b3];     p1 = bounds[b3 + 1];
                p2 = bounds[b3 + 2]; p3 = bounds[b3 + 3];
            } else {
                p0 = (b3 == 0) ? 0 : bounds[b3 - 1];
                p1 = bounds[b3]; p2 = bounds[b3 + 1]; p3 = bounds[b3 + 2];
            }
            beg[0] = p0; en[0] = p1;
            beg[1] = p1; en[1] = p2;
            beg[2] = p2; en[2] = p3;
            inv = 1.0f / fmaxf((float)(p3 - p0), 1.0f);
            if (FAST) {
                r0 = xh[n*16 + c2];
                r1 = xh[n*16 + c2 + 1];
            } else {
                #pragma unroll
                for (int i = 0; i < 4; i++) {
                    float4 xv = xb[n*32 + c4 + i];
                    xf[4*i+0] = xv.x; xf[4*i+1] = xv.y;
                    xf[4*i+2] = xv.z; xf[4*i+3] = xv.w;
                }
            }
        }
        #pragma unroll
        for (int r = 0; r < NREL; r++) {
            float acc[16];
            #pragma unroll
            for (int i = 0; i < 16; i++) acc[i] = 0.f;
            int p = beg[r], pe = en[r];
            if (FAST) {
                for (; p + 1 < pe; p += 2) {
                    int sA = epack[p], sB = epack[p+1];
                    uint4 ua = xh[sA*16 + c2], ub = xh[sA*16 + c2 + 1];
                    uint4 va = xh[sB*16 + c2], vb = xh[sB*16 + c2 + 1];
                    acc[0]  += blo(ua.x) + blo(va.x); acc[1]  += bhi(ua.x) + bhi(va.x);
                    acc[2]  += blo(ua.y) + blo(va.y); acc[3]  += bhi(ua.y) + bhi(va.y);
                    acc[4]  += blo(ua.z) + blo(va.z); acc[5]  += bhi(ua.z) + bhi(va.z);
                    acc[6]  += blo(ua.w) + blo(va.w); acc[7]  += bhi(ua.w) + bhi(va.w);
                    acc[8]  += blo(ub.x) + blo(vb.x); acc[9]  += bhi(ub.x) + bhi(vb.x);
                    acc[10] += blo(ub.y) + blo(vb.y); acc[11] += bhi(ub.y) + bhi(vb.y);
                    acc[12] += blo(ub.z) + blo(vb.z); acc[13] += bhi(ub.z) + bhi(vb.z);
                    acc[14] += blo(ub.w) + blo(vb.w); acc[15] += bhi(ub.w) + bhi(vb.w);
                }
                if (p < pe) {
                    int sA = epack[p];
                    uint4 ua = xh[sA*16 + c2], ub = xh[sA*16 + c2 + 1];
                    acc[0]  += blo(ua.x); acc[1]  += bhi(ua.x);
                    acc[2]  += blo(ua.y); acc[3]  += bhi(ua.y);
                    acc[4]  += blo(ua.z); acc[5]  += bhi(ua.z);
                    acc[6]  += blo(ua.w); acc[7]  += bhi(ua.w);
                    acc[8]  += blo(ub.x); acc[9]  += bhi(ub.x);
                    acc[10] += blo(ub.y); acc[11] += bhi(ub.y);
                    acc[12] += blo(ub.z); acc[13] += bhi(ub.z);
                    acc[14] += blo(ub.w); acc[15] += bhi(ub.w);
                }
            } else {
                for (; p + 1 < pe; p += 2) {
                    int sA = epack[p], sB = epack[p+1];
                    float4 u0 = xb[sA*32 + c4 + 0];
                    float4 u1 = xb[sA*32 + c4 + 1];
                    float4 u2 = xb[sA*32 + c4 + 2];
                    float4 u3 = xb[sA*32 + c4 + 3];
                    float4 v0 = xb[sB*32 + c4 + 0];
                    float4 v1 = xb[sB*32 + c4 + 1];
                    float4 v2 = xb[sB*32 + c4 + 2];
                    float4 v3 = xb[sB*32 + c4 + 3];
                    acc[0]  += u0.x + v0.x; acc[1]  += u0.y + v0.y;
                    acc[2]  += u0.z + v0.z; acc[3]  += u0.w + v0.w;
                    acc[4]  += u1.x + v1.x; acc[5]  += u1.y + v1.y;
                    acc[6]  += u1.z + v1.z; acc[7]  += u1.w + v1.w;
                    acc[8]  += u2.x + v2.x; acc[9]  += u2.y + v2.y;
                    acc[10] += u2.z + v2.z; acc[11] += u2.w + v2.w;
                    acc[12] += u3.x + v3.x; acc[13] += u3.y + v3.y;
                    acc[14] += u3.z + v3.z; acc[15] += u3.w + v3.w;
                }
                if (p < pe) {
                    int sA = epack[p];
                    float4 u0 = xb[sA*32 + c4 + 0];
                    float4 u1 = xb[sA*32 + c4 + 1];
                    float4 u2 = xb[sA*32 + c4 + 2];
                    float4 u3 = xb[sA*32 + c4 + 3];
                    acc[0]  += u0.x; acc[1]  += u0.y; acc[2]  += u0.z; acc[3]  += u0.w;
                    acc[4]  += u1.x; acc[5]  += u1.y; acc[6]  += u1.z; acc[7]  += u1.w;
                    acc[8]  += u2.x; acc[9]  += u2.y; acc[10] += u2.z; acc[11] += u2.w;
                    acc[12] += u3.x; acc[13] += u3.y; acc[14] += u3.z; acc[15] += u3.w;
                }
            }
            uint4 w0, w1;
            w0.x = packbf(acc[0]*inv,  acc[1]*inv);  w0.y = packbf(acc[2]*inv,  acc[3]*inv);
            w0.z = packbf(acc[4]*inv,  acc[5]*inv);  w0.w = packbf(acc[6]*inv,  acc[7]*inv);
            w1.x = packbf(acc[8]*inv,  acc[9]*inv);  w1.y = packbf(acc[10]*inv, acc[11]*inv);
            w1.z = packbf(acc[12]*inv, acc[13]*inv); w1.w = packbf(acc[14]*inv, acc[15]*inv);
            int k = r*DIM + 16*c;
            Af[SW(fo(m, k))]     = w0;
            Af[SW(fo(m, k + 8))] = w1;
        }
        {   // residual (x itself) A-frag
            uint4 w0, w1;
            if (FAST) {
                w0 = r0; w1 = r1;                    // already bf16-packed
            } else {
                w0.x = packbf(xf[0],  xf[1]);  w0.y = packbf(xf[2],  xf[3]);
                w0.z = packbf(xf[4],  xf[5]);  w0.w = packbf(xf[6],  xf[7]);
                w1.x = packbf(xf[8],  xf[9]);  w1.y = packbf(xf[10], xf[11]);
                w1.z = packbf(xf[12], xf[13]); w1.w = packbf(xf[14], xf[15]);
            }
            int k = KS + 16*c;
            Af[SW(fo(m, k))]     = w0;
            Af[SW(fo(m, k + 8))] = w1;
        }
    }
    __syncthreads();

    // ---------------- MFMA GEMM ----------------
    const int lane = t & 63;
    const int w    = t >> 6;                // 0..1 (wave)
    const int mm   = lane & 15;
    const int q    = lane >> 4;
    f32x4 acc0 = {0,0,0,0}, acc1 = {0,0,0,0}, acc2 = {0,0,0,0}, acc3 = {0,0,0,0};
    {
        const short8* Aq = (const short8*)Af;
        const short8* Bq = (const short8*)Bpack;
        #pragma unroll
        for (int kk = 0; kk < 16; kk++) {
            short8 a  = Aq[SW(kk*64 + lane)];
            short8 b0 = Bq[((w*4 + 0)*16 + kk)*64 + lane];
            short8 b1 = Bq[((w*4 + 1)*16 + kk)*64 + lane];
            short8 b2 = Bq[((w*4 + 2)*16 + kk)*64 + lane];
            short8 b3 = Bq[((w*4 + 3)*16 + kk)*64 + lane];
            acc0 = __builtin_amdgcn_mfma_f32_16x16x32_bf16(a, b0, acc0, 0, 0, 0);
            acc1 = __builtin_amdgcn_mfma_f32_16x16x32_bf16(a, b1, acc1, 0, 0, 0);
            acc2 = __builtin_amdgcn_mfma_f32_16x16x32_bf16(a, b2, acc2, 0, 0, 0);
            acc3 = __builtin_amdgcn_mfma_f32_16x16x32_bf16(a, b3, acc3, 0, 0, 0);
        }
    }
    __syncthreads();                        // all A reads done; reuse as H

    float* H = (float*)Af;                  // H[16][132] = 8448 B < 16 KiB
    {
        int rb = q * 4;
        #pragma unroll
        for (int nt = 0; nt < 4; nt++) {
            int d = (w*4 + nt)*16 + mm;
            float lb = linb[d];
            f32x4 a = (nt == 0) ? acc0 : (nt == 1) ? acc1 : (nt == 2) ? acc2 : acc3;
            #pragma unroll
            for (int i = 0; i < 4; i++)
                H[(rb + i)*132 + d] = a[i] + lb;
        }
    }
    __syncthreads();

    // ---------------- LayerNorm stats ----------------
    {
        int j = t >> 3, p = t & 7;
        float s1 = 0.f, s2 = 0.f;
        const float* hr = &H[j*132 + p*16];
        #pragma unroll
        for (int i = 0; i < 16; i++) { float v = hr[i]; s1 += v; s2 += v*v; }
        #pragma unroll
        for (int off = 1; off < 8; off <<= 1) {
            s1 += __shfl_xor(s1, off);
            s2 += __shfl_xor(s2, off);
        }
        if (p == 0) {
            float mu  = s1 * (1.0f/DIM);
            float var = s2 * (1.0f/DIM) - mu*mu;
            s_mu[j] = mu;
            s_rs[j] = rsqrtf(var + LN_EPS);
        }
    }
    __syncthreads();

    // ---------------- output (fp32) ----------------
    {
        int d = t;
        float g = gamma[d];
        float b = beta[d];
        for (int j = 0; j < NB; j++) {
            int n = n0 + j;
            if (n < N) {
                float hv = H[j*132 + d];
                out[(size_t)n*DIM + d] = g * (hv - s_mu[j]) * s_rs[j] + b;
            }
        }
    }
}

extern "C" void kernel_launch(void* const* d_in, const int* in_sizes, int n_in,
                              void* d_out, int out_size, void* d_ws, size_t ws_size,
                              hipStream_t stream)
{
    const float* x   = (const float*)d_in[0];
    const int*   ei  = (const int*)d_in[1];
    const int*   et  = (const int*)d_in[2];
    const float* rw  = (const float*)d_in[3];
    const float* lw  = (const float*)d_in[4];
    const float* lb  = (const float*)d_in[5];
    const float* lg  = (const float*)d_in[6];
    const float* lbe = (const float*)d_in[7];

    const int N  = in_sizes[0] / DIM;
    const int E  = in_sizes[2];
    const int M3 = 3 * N;
    const int NBLK = (M3 + 1023) / 1024;           // scan blocks (any count ok)

    // ws layout — core 3.13 MB; fast path adds rank arrays + bf16 x.
    char* w = (char*)d_ws;
    uint* part = (uint*)w;                w += (size_t)NBLK * 4;
    int* work  = (int*)w;                 w += ((size_t)M3 + 8) * 4;   // +sentinel
    int* epack = (int*)w;                 w += (size_t)E * 4;          // 2.4 MB
    w = (char*)(((uintptr_t)w + 15) & ~(uintptr_t)15);
    unsigned short* Bpack = (unsigned short*)w;    w += 512 * 128 * 2; // 128 KB
    w = (char*)(((uintptr_t)w + 15) & ~(uintptr_t)15);
    int* dst3 = (int*)w;                  w += (size_t)E * 4;
    int* srcv = (int*)w;                  w += (size_t)E * 4;
    int* rkv  = (int*)w;                  w += (size_t)E * 4;
    w = (char*)(((uintptr_t)w + 15) & ~(uintptr_t)15);
    unsigned short* xbf = (unsigned short*)w;      w += (size_t)N * DIM * 2;
    const size_t need_fast = (size_t)(w - (char*)d_ws);
    const bool fast = (ws_size >= need_fast);      // constant across calls

    const int EB = (E + 255) / 256;

    // zero part[] (lookback status) + work[] (+sentinel slot) in one memset
    hipMemsetAsync(d_ws, 0, (size_t)(NBLK + M3 + 8) * 4, stream);

    if (fast) {
        prep_fast<<<EB, 256, 0, stream>>>(ei, et, x, E, N, work,
                                          dst3, srcv, rkv, rw, lw, Bpack, xbf);
    } else {
        prep_slow<<<EB, 256, 0, stream>>>(ei, et, E, work, rw, lw, Bpack);
    }

    scan_kernel<<<NBLK, 256, 0, stream>>>(work, part, M3, NBLK);

    if (fast) {
        fill_fast<<<EB, 256, 0, stream>>>(dst3, srcv, rkv, E, work, epack);
        main_kernel<1><<<(N + NB - 1)/NB, 128, 0, stream>>>(x, xbf, work, epack, Bpack,
                                                            lb, lg, lbe, (float*)d_out, N);
    } else {
        fill_slow<<<EB, 256, 0, stream>>>(ei, et, E, work, epack);
        main_kernel<0><<<(N + NB - 1)/NB, 128, 0, stream>>>(x, xbf, work, epack, Bpack,
                                                            lb, lg, lbe, (float*)d_out, N);
    }
}